// Round 1
// baseline (232.819 us; speedup 1.0000x reference)
//
#include <hip/hip_runtime.h>

typedef unsigned short u16;
typedef unsigned int   u32;
typedef __attribute__((ext_vector_type(8)))  short short8;
typedef __attribute__((ext_vector_type(4)))  float f32x4v;

#define DEVI __device__ __forceinline__

constexpr int   Bb = 32, Nn = 4096, Dd = 256, Kk = 8, SDd = 64, HDd = 128;
constexpr float EPSc = 1e-8f, LNEPS = 1e-5f, SCALEc = 0.125f;  // SD^-0.5

DEVI u16 f2b(float f) {            // f32 -> bf16 RNE
  u32 u = __builtin_bit_cast(u32, f);
  return (u16)((u + 0x7fffu + ((u >> 16) & 1u)) >> 16);
}
DEVI float b2f(u16 s) { return __builtin_bit_cast(float, ((u32)s) << 16); }
DEVI float sigmoidf_(float x) { return 1.f / (1.f + __expf(-x)); }

DEVI float dot64(const float* __restrict__ a, const float* __restrict__ w) {
  float s = 0.f;
  #pragma unroll
  for (int i = 0; i < 16; ++i) {
    float4 av = *(const float4*)(a + i * 4);
    float4 wv = *(const float4*)(w + i * 4);
    s += av.x * wv.x + av.y * wv.y + av.z * wv.z + av.w * wv.w;
  }
  return s;
}
DEVI float dot128(const float* __restrict__ a, const float* __restrict__ w) {
  float s = 0.f;
  #pragma unroll
  for (int i = 0; i < 32; ++i) {
    float4 av = *(const float4*)(a + i * 4);
    float4 wv = *(const float4*)(w + i * 4);
    s += av.x * wv.x + av.y * wv.y + av.z * wv.z + av.w * wv.w;
  }
  return s;
}

// LayerNorm of 8 rows x 64 cols living in LDS (256 threads).
DEVI void ln8(const float* src, float* dst, const float* __restrict__ g,
              const float* __restrict__ b, int t) {
  int l = t & 63, w = t >> 6;
  int r = w * 2 + (l >> 5), c = l & 31;
  float x0 = src[r * 64 + c], x1 = src[r * 64 + c + 32];
  float s = x0 + x1, q2 = x0 * x0 + x1 * x1;
  #pragma unroll
  for (int m = 1; m < 32; m <<= 1) { s += __shfl_xor(s, m); q2 += __shfl_xor(q2, m); }
  float mean = s * (1.f / 64.f);
  float rs = rsqrtf(q2 * (1.f / 64.f) - mean * mean + LNEPS);
  dst[r * 64 + c]      = (x0 - mean) * rs * g[c]      + b[c];
  dst[r * 64 + c + 32] = (x1 - mean) * rs * g[c + 32] + b[c + 32];
}

// ---------------------------------------------------------------------------
// K1: fused LN(256) -> proj(256->64)+bias -> LN(64) -> k,v (64->64), bf16 out.
// 64 rows/block, 4 waves x 16 rows, mfma_f32_16x16x32_bf16.
// A-frag: lane holds row=l&15, k-chunk 8*(l>>4); B-frag symmetric (col=l&15).
// D-frag: col=lane&15, row=(lane>>4)*4+reg (m89-verified).
// ---------------------------------------------------------------------------
__global__ __launch_bounds__(256) void k_proj_kv(
    const float* __restrict__ in, const float* __restrict__ gpro,
    const float* __restrict__ bpro, const float* __restrict__ Wp,
    const float* __restrict__ bproj, const float* __restrict__ gin,
    const float* __restrict__ bin, const float* __restrict__ Wk,
    const float* __restrict__ Wv, u16* __restrict__ k_ws, u16* __restrict__ v_ws) {
  __shared__ __align__(16) u16 wp_lds[64 * 256];
  __shared__ __align__(16) u16 wk_lds[64 * 64];
  __shared__ __align__(16) u16 wv_lds[64 * 64];
  __shared__ __align__(16) u16 xn_lds[64 * 64];
  __shared__ float gp_l[256], bp_l[256], bj_l[64], gn_l[64], bn_l[64];

  const int t = threadIdx.x;
  // stage W_proj (bf16, XOR-swizzled rows: byte ^= (row&7)<<4)
  #pragma unroll 4
  for (int j = 0; j < 64; ++j) {
    int byte = (j * 512 + 2 * t) ^ ((j & 7) << 4);
    *(u16*)((char*)wp_lds + byte) = f2b(Wp[j * 256 + t]);
  }
  #pragma unroll 4
  for (int j = 0; j < 16; ++j) {
    int idx = j * 256 + t;
    int n = idx >> 6, k = idx & 63;
    int byte = (n * 128 + 2 * k) ^ ((n & 7) << 4);
    *(u16*)((char*)wk_lds + byte) = f2b(Wk[idx]);
    *(u16*)((char*)wv_lds + byte) = f2b(Wv[idx]);
  }
  gp_l[t] = gpro[t];
  bp_l[t] = bpro[t];
  if (t < 64) { bj_l[t] = bproj[t]; gn_l[t] = gin[t]; bn_l[t] = bin[t]; }
  __syncthreads();

  const int l = t & 63, w = t >> 6;
  const int r16 = l & 15, q4 = l >> 4;
  const long rowbase = (long)blockIdx.x * 64 + w * 16;
  const long grow = rowbase + r16;
  const float* rp = in + grow * 256;

  // load this lane's slices of its row; stats in f32, values packed to bf16
  short8 a[8];
  float sum = 0.f, sq = 0.f;
  #pragma unroll
  for (int ks = 0; ks < 8; ++ks) {
    float4 L0 = *(const float4*)(rp + ks * 32 + q4 * 8);
    float4 L1 = *(const float4*)(rp + ks * 32 + q4 * 8 + 4);
    sum += L0.x + L0.y + L0.z + L0.w + L1.x + L1.y + L1.z + L1.w;
    sq += L0.x * L0.x + L0.y * L0.y + L0.z * L0.z + L0.w * L0.w +
          L1.x * L1.x + L1.y * L1.y + L1.z * L1.z + L1.w * L1.w;
    a[ks][0] = (short)f2b(L0.x); a[ks][1] = (short)f2b(L0.y);
    a[ks][2] = (short)f2b(L0.z); a[ks][3] = (short)f2b(L0.w);
    a[ks][4] = (short)f2b(L1.x); a[ks][5] = (short)f2b(L1.y);
    a[ks][6] = (short)f2b(L1.z); a[ks][7] = (short)f2b(L1.w);
  }
  // row r16 lives in lanes {r16, r16+16, r16+32, r16+48}
  sum += __shfl_xor(sum, 16); sum += __shfl_xor(sum, 32);
  sq  += __shfl_xor(sq, 16);  sq  += __shfl_xor(sq, 32);
  float mean = sum * (1.f / 256.f);
  float rs = rsqrtf(sq * (1.f / 256.f) - mean * mean + LNEPS);
  #pragma unroll
  for (int ks = 0; ks < 8; ++ks) {
    #pragma unroll
    for (int j = 0; j < 8; ++j) {
      int kidx = ks * 32 + q4 * 8 + j;
      float x = b2f((u16)a[ks][j]);
      a[ks][j] = (short)f2b((x - mean) * rs * gp_l[kidx] + bp_l[kidx]);
    }
  }

  // proj GEMM: 16 rows x 64 cols, K=256
  f32x4v acc[4];
  #pragma unroll
  for (int nt = 0; nt < 4; ++nt)
    #pragma unroll
    for (int i = 0; i < 4; ++i) acc[nt][i] = 0.f;
  #pragma unroll
  for (int ks = 0; ks < 8; ++ks) {
    #pragma unroll
    for (int nt = 0; nt < 4; ++nt) {
      int n = nt * 16 + r16;
      int byte = (n * 512 + 64 * ks + 16 * q4) ^ ((n & 7) << 4);
      short8 bf = *(const short8*)((const char*)wp_lds + byte);
      acc[nt] = __builtin_amdgcn_mfma_f32_16x16x32_bf16(a[ks], bf, acc[nt], 0, 0, 0);
    }
  }
  // + b_proj
  #pragma unroll
  for (int nt = 0; nt < 4; ++nt) {
    float bb = bj_l[nt * 16 + r16];
    #pragma unroll
    for (int reg = 0; reg < 4; ++reg) acc[nt][reg] += bb;
  }
  // LN(64) per output row; write xn (bf16, swizzled) to LDS
  #pragma unroll
  for (int reg = 0; reg < 4; ++reg) {
    float s = acc[0][reg] + acc[1][reg] + acc[2][reg] + acc[3][reg];
    float q2 = acc[0][reg] * acc[0][reg] + acc[1][reg] * acc[1][reg] +
               acc[2][reg] * acc[2][reg] + acc[3][reg] * acc[3][reg];
    #pragma unroll
    for (int m = 1; m < 16; m <<= 1) { s += __shfl_xor(s, m); q2 += __shfl_xor(q2, m); }
    float mn = s * (1.f / 64.f);
    float rr = rsqrtf(q2 * (1.f / 64.f) - mn * mn + LNEPS);
    int row = q4 * 4 + reg;       // 0..15 within wave tile
    int rowg = w * 16 + row;
    #pragma unroll
    for (int nt = 0; nt < 4; ++nt) {
      int col = nt * 16 + r16;
      float y = (acc[nt][reg] - mn) * rr * gn_l[col] + bn_l[col];
      int byte = (rowg * 128 + 2 * col) ^ ((row & 7) << 4);
      *(u16*)((char*)xn_lds + byte) = f2b(y);
    }
  }
  __syncthreads();

  // k,v GEMMs: K=64
  f32x4v kacc[4], vacc[4];
  #pragma unroll
  for (int nt = 0; nt < 4; ++nt)
    #pragma unroll
    for (int i = 0; i < 4; ++i) { kacc[nt][i] = 0.f; vacc[nt][i] = 0.f; }
  #pragma unroll
  for (int ks = 0; ks < 2; ++ks) {
    int rowg2 = w * 16 + r16;
    int abyte = (rowg2 * 128 + 64 * ks + 16 * q4) ^ ((r16 & 7) << 4);
    short8 af = *(const short8*)((const char*)xn_lds + abyte);
    #pragma unroll
    for (int nt = 0; nt < 4; ++nt) {
      int n = nt * 16 + r16;
      int bbyte = (n * 128 + 64 * ks + 16 * q4) ^ ((n & 7) << 4);
      short8 bk = *(const short8*)((const char*)wk_lds + bbyte);
      short8 bv = *(const short8*)((const char*)wv_lds + bbyte);
      kacc[nt] = __builtin_amdgcn_mfma_f32_16x16x32_bf16(af, bk, kacc[nt], 0, 0, 0);
      vacc[nt] = __builtin_amdgcn_mfma_f32_16x16x32_bf16(af, bv, vacc[nt], 0, 0, 0);
    }
  }
  #pragma unroll
  for (int nt = 0; nt < 4; ++nt) {
    #pragma unroll
    for (int reg = 0; reg < 4; ++reg) {
      int row = q4 * 4 + reg;
      long gr = rowbase + row;
      int col = nt * 16 + r16;
      long o = gr * 64 + col;
      k_ws[o] = f2b(kacc[nt][reg]);
      v_ws[o] = f2b(vacc[nt][reg]);
    }
  }
}

// ---------------------------------------------------------------------------
// K2: per (b, n-chunk of 512): recompute sn,q; logits; softmax over slots;
// accumulate S=sum_n attn and U=sum_n attn*v partials.
// ---------------------------------------------------------------------------
__global__ __launch_bounds__(256) void k_attn(
    const float* __restrict__ slots_in, int init_slots,
    const float* __restrict__ noise, const float* __restrict__ mu,
    const float* __restrict__ ls, const float* __restrict__ gs,
    const float* __restrict__ bs, const float* __restrict__ Wq,
    const u16* __restrict__ k_ws, const u16* __restrict__ v_ws,
    float* __restrict__ S_part, float* __restrict__ U_part) {
  const int bx = blockIdx.x, by = blockIdx.y, t = threadIdx.x;
  __shared__ float sl[512], snl[512], ql[512];
  __shared__ __align__(16) float attn_l[256 * 8];
  __shared__ __align__(16) u16 v_l[256 * 64];
  __shared__ float ured[2048], sred[32];

  for (int i = t; i < 512; i += 256) {
    float v;
    if (init_slots) { int d = i & 63; v = mu[d] + __expf(ls[d]) * noise[by * 512 + i]; }
    else v = slots_in[by * 512 + i];
    sl[i] = v;
  }
  __syncthreads();
  ln8(sl, snl, gs, bs, t);
  __syncthreads();
  {
    int kk = t >> 6, d = t & 63;
    ql[kk * 64 + d]       = SCALEc * dot64(snl + kk * 64, Wq + d * 64);
    ql[(kk + 4) * 64 + d] = SCALEc * dot64(snl + (kk + 4) * 64, Wq + d * 64);
  }
  __syncthreads();

  float s8[8];
  float au[8][2];
  #pragma unroll
  for (int i = 0; i < 8; ++i) { s8[i] = 0.f; au[i][0] = 0.f; au[i][1] = 0.f; }

  const int l = t & 63, w = t >> 6, p = l & 31, g = l >> 5;
  for (int sub = 0; sub < 2; ++sub) {
    const int nb = bx * 512 + sub * 256;
    {  // stage v tile (linear copy -> conflict-free)
      const uint4* src = (const uint4*)(v_ws + ((long)by * Nn + nb) * 64);
      uint4* dst = (uint4*)v_l;
      #pragma unroll
      for (int i = 0; i < 8; ++i) dst[t + i * 256] = src[t + i * 256];
    }
    {  // logits + softmax over slots for n = nb+t
      const u32* kr = (const u32*)(k_ws + ((long)by * Nn + nb + t) * 64);
      u32 kw[32];
      #pragma unroll
      for (int i = 0; i < 32; ++i) kw[i] = kr[i];
      float lg[8];
      #pragma unroll
      for (int i = 0; i < 8; ++i) lg[i] = 0.f;
      #pragma unroll
      for (int c4 = 0; c4 < 16; ++c4) {
        u32 wa = kw[2 * c4], wb = kw[2 * c4 + 1];
        float f0 = b2f((u16)(wa & 0xffff)), f1 = b2f((u16)(wa >> 16));
        float f2v = b2f((u16)(wb & 0xffff)), f3 = b2f((u16)(wb >> 16));
        #pragma unroll
        for (int kk = 0; kk < 8; ++kk) {
          float4 qv = *(const float4*)(ql + kk * 64 + c4 * 4);
          lg[kk] += qv.x * f0 + qv.y * f1 + qv.z * f2v + qv.w * f3;
        }
      }
      float mx = lg[0];
      #pragma unroll
      for (int kk = 1; kk < 8; ++kk) mx = fmaxf(mx, lg[kk]);
      float e[8], ss = 0.f;
      #pragma unroll
      for (int kk = 0; kk < 8; ++kk) { e[kk] = __expf(lg[kk] - mx); ss += e[kk]; }
      float inv = 1.f / ss;
      #pragma unroll
      for (int kk = 0; kk < 8; ++kk) { e[kk] *= inv; s8[kk] += e[kk]; }
      float4 A0 = {e[0], e[1], e[2], e[3]}, A1 = {e[4], e[5], e[6], e[7]};
      *(float4*)(attn_l + t * 8) = A0;
      *(float4*)(attn_l + t * 8 + 4) = A1;
    }
    __syncthreads();
    // attn @ v : wave owns 64-n strip, lane owns d-pair p (d=2p,2p+1)
    #pragma unroll 4
    for (int nn = 0; nn < 32; ++nn) {
      int n = w * 64 + nn * 2 + g;
      float4 a0 = *(const float4*)(attn_l + n * 8);
      float4 a1 = *(const float4*)(attn_l + n * 8 + 4);
      u32 vv = ((const u32*)v_l)[n * 32 + p];
      float vlo = b2f((u16)(vv & 0xffff)), vhi = b2f((u16)(vv >> 16));
      au[0][0] += a0.x * vlo; au[0][1] += a0.x * vhi;
      au[1][0] += a0.y * vlo; au[1][1] += a0.y * vhi;
      au[2][0] += a0.z * vlo; au[2][1] += a0.z * vhi;
      au[3][0] += a0.w * vlo; au[3][1] += a0.w * vhi;
      au[4][0] += a1.x * vlo; au[4][1] += a1.x * vhi;
      au[5][0] += a1.y * vlo; au[5][1] += a1.y * vhi;
      au[6][0] += a1.z * vlo; au[6][1] += a1.z * vhi;
      au[7][0] += a1.w * vlo; au[7][1] += a1.w * vhi;
    }
    __syncthreads();
  }
  #pragma unroll
  for (int kk = 0; kk < 8; ++kk) {
    au[kk][0] += __shfl_xor(au[kk][0], 32);
    au[kk][1] += __shfl_xor(au[kk][1], 32);
  }
  if (l < 32) {
    #pragma unroll
    for (int kk = 0; kk < 8; ++kk) {
      ured[w * 512 + kk * 64 + 2 * p] = au[kk][0];
      ured[w * 512 + kk * 64 + 2 * p + 1] = au[kk][1];
    }
  }
  #pragma unroll
  for (int kk = 0; kk < 8; ++kk) {
    #pragma unroll
    for (int m = 1; m < 64; m <<= 1) s8[kk] += __shfl_xor(s8[kk], m);
  }
  if (l == 0) {
    #pragma unroll
    for (int kk = 0; kk < 8; ++kk) sred[w * 8 + kk] = s8[kk];
  }
  __syncthreads();
  for (int i = t; i < 512; i += 256)
    U_part[((long)(by * 8 + bx)) * 512 + i] =
        ured[i] + ured[512 + i] + ured[1024 + i] + ured[1536 + i];
  if (t < 8)
    S_part[(by * 8 + bx) * 8 + t] = sred[t] + sred[8 + t] + sred[16 + t] + sred[24 + t];
}

// ---------------------------------------------------------------------------
// K3: reduce partials, updates = U/(S+eps), GRU, residual MLP -> new slots.
// ---------------------------------------------------------------------------
__global__ __launch_bounds__(256) void k_update(
    const float* __restrict__ S_part, const float* __restrict__ U_part,
    const float* __restrict__ slots_in, int init_slots,
    const float* __restrict__ noise, const float* __restrict__ mu,
    const float* __restrict__ ls, const float* __restrict__ W_ih,
    const float* __restrict__ W_hh, const float* __restrict__ b_ih,
    const float* __restrict__ b_hh, const float* __restrict__ gm,
    const float* __restrict__ bm, const float* __restrict__ W1,
    const float* __restrict__ b1, const float* __restrict__ W2,
    const float* __restrict__ b2, float* __restrict__ slots_out,
    float* __restrict__ out_slots, int write_out) {
  const int b = blockIdx.x, t = threadIdx.x;
  __shared__ float u_l[512], sp[512], gi[1536], gh[1536], sn2[512], mi[512],
      h1[1024], Ssum[8];
  if (t < 8) {
    float s = 0.f;
    #pragma unroll
    for (int ch = 0; ch < 8; ++ch) s += S_part[(b * 8 + ch) * 8 + t];
    Ssum[t] = s;
  }
  for (int i = t; i < 512; i += 256) {
    float v;
    if (init_slots) { int d = i & 63; v = mu[d] + __expf(ls[d]) * noise[b * 512 + i]; }
    else v = slots_in[b * 512 + i];
    sp[i] = v;
  }
  __syncthreads();
  for (int i = t; i < 512; i += 256) {
    float s = 0.f;
    #pragma unroll
    for (int ch = 0; ch < 8; ++ch) s += U_part[(b * 8 + ch) * 512 + i];
    u_l[i] = s / (Ssum[i >> 6] + EPSc);
  }
  __syncthreads();
  for (int i = t; i < 1536; i += 256) {
    int kk = i / 192, j = i - kk * 192;
    gi[i] = b_ih[j] + dot64(u_l + kk * 64, W_ih + j * 64);
    gh[i] = b_hh[j] + dot64(sp + kk * 64, W_hh + j * 64);
  }
  __syncthreads();
  for (int i = t; i < 512; i += 256) {
    int kk = i >> 6, d = i & 63, base = kk * 192;
    float r = sigmoidf_(gi[base + d] + gh[base + d]);
    float z = sigmoidf_(gi[base + 64 + d] + gh[base + 64 + d]);
    float nn = tanhf(gi[base + 128 + d] + r * gh[base + 128 + d]);
    sn2[i] = (1.f - z) * nn + z * sp[i];
  }
  __syncthreads();
  ln8(sn2, mi, gm, bm, t);
  __syncthreads();
  for (int i = t; i < 1024; i += 256) {
    int kk = i >> 7, j = i & 127;
    h1[i] = fmaxf(b1[j] + dot64(mi + kk * 64, W1 + j * 64), 0.f);
  }
  __syncthreads();
  for (int i = t; i < 512; i += 256) {
    int kk = i >> 6, d = i & 63;
    float s = sn2[i] + b2[d] + dot128(h1 + kk * 128, W2 + d * 128);
    slots_out[b * 512 + i] = s;
    if (write_out) out_slots[b * 512 + i] = s;
  }
}

// ---------------------------------------------------------------------------
// K4: final attention -> d_out (f32), softmax over slots, not n-normalized.
// ---------------------------------------------------------------------------
__global__ __launch_bounds__(256) void k_final(
    const float* __restrict__ slots_in, const float* __restrict__ gs,
    const float* __restrict__ bs, const float* __restrict__ Wq,
    const u16* __restrict__ k_ws, float* __restrict__ outA) {
  const int bx = blockIdx.x, by = blockIdx.y, t = threadIdx.x;
  __shared__ float sl[512], snl[512], ql[512];
  for (int i = t; i < 512; i += 256) sl[i] = slots_in[by * 512 + i];
  __syncthreads();
  ln8(sl, snl, gs, bs, t);
  __syncthreads();
  {
    int kk = t >> 6, d = t & 63;
    ql[kk * 64 + d]       = SCALEc * dot64(snl + kk * 64, Wq + d * 64);
    ql[(kk + 4) * 64 + d] = SCALEc * dot64(snl + (kk + 4) * 64, Wq + d * 64);
  }
  __syncthreads();
  for (int sub = 0; sub < 2; ++sub) {
    int n = bx * 512 + sub * 256 + t;
    const u32* kr = (const u32*)(k_ws + ((long)by * Nn + n) * 64);
    u32 kw[32];
    #pragma unroll
    for (int i = 0; i < 32; ++i) kw[i] = kr[i];
    float lg[8];
    #pragma unroll
    for (int i = 0; i < 8; ++i) lg[i] = 0.f;
    #pragma unroll
    for (int c4 = 0; c4 < 16; ++c4) {
      u32 wa = kw[2 * c4], wb = kw[2 * c4 + 1];
      float f0 = b2f((u16)(wa & 0xffff)), f1 = b2f((u16)(wa >> 16));
      float f2v = b2f((u16)(wb & 0xffff)), f3 = b2f((u16)(wb >> 16));
      #pragma unroll
      for (int kk = 0; kk < 8; ++kk) {
        float4 qv = *(const float4*)(ql + kk * 64 + c4 * 4);
        lg[kk] += qv.x * f0 + qv.y * f1 + qv.z * f2v + qv.w * f3;
      }
    }
    float mx = lg[0];
    #pragma unroll
    for (int kk = 1; kk < 8; ++kk) mx = fmaxf(mx, lg[kk]);
    float e[8], ss = 0.f;
    #pragma unroll
    for (int kk = 0; kk < 8; ++kk) { e[kk] = __expf(lg[kk] - mx); ss += e[kk]; }
    float inv = 1.f / ss;
    #pragma unroll
    for (int kk = 0; kk < 8; ++kk)
      outA[((long)by * 8 + kk) * 4096 + n] = e[kk] * inv;
  }
}

extern "C" void kernel_launch(void* const* d_in, const int* in_sizes, int n_in,
                              void* d_out, int out_size, void* d_ws, size_t ws_size,
                              hipStream_t stream) {
  (void)in_sizes; (void)n_in; (void)out_size; (void)ws_size;
  const float* in    = (const float*)d_in[0];
  const float* noise = (const float*)d_in[1];
  const float* mu    = (const float*)d_in[2];
  const float* ls    = (const float*)d_in[3];
  const float* gpro  = (const float*)d_in[4];
  const float* bpro  = (const float*)d_in[5];
  const float* Wp    = (const float*)d_in[6];
  const float* bproj = (const float*)d_in[7];
  const float* Wq    = (const float*)d_in[8];
  const float* Wk    = (const float*)d_in[9];
  const float* Wv    = (const float*)d_in[10];
  const float* W_ih  = (const float*)d_in[11];
  const float* W_hh  = (const float*)d_in[12];
  const float* b_ih  = (const float*)d_in[13];
  const float* b_hh  = (const float*)d_in[14];
  const float* W1    = (const float*)d_in[15];
  const float* b1    = (const float*)d_in[16];
  const float* W2    = (const float*)d_in[17];
  const float* b2    = (const float*)d_in[18];
  const float* gin   = (const float*)d_in[19];
  const float* bin   = (const float*)d_in[20];
  const float* gs    = (const float*)d_in[21];
  const float* bs    = (const float*)d_in[22];
  const float* gm    = (const float*)d_in[23];
  const float* bm    = (const float*)d_in[24];

  char* ws = (char*)d_ws;
  u16* k_ws   = (u16*)ws;                                   // 16 MiB
  u16* v_ws   = (u16*)(ws + 16777216);                      // 16 MiB
  float* slots_a = (float*)(ws + 33554432);                 // 64 KiB
  float* slots_b = (float*)(ws + 33554432 + 65536);         // 64 KiB
  float* S_part  = (float*)(ws + 33554432 + 131072);        // 8 KiB
  float* U_part  = (float*)(ws + 33554432 + 131072 + 8192); // 512 KiB
  float* out = (float*)d_out;

  k_proj_kv<<<dim3(2048), dim3(256), 0, stream>>>(in, gpro, bpro, Wp, bproj, gin,
                                                  bin, Wk, Wv, k_ws, v_ws);
  dim3 g2(8, 32), blk(256);
  // iter 0 (slots initialized in-kernel from mu/ls/noise)
  k_attn<<<g2, blk, 0, stream>>>(slots_a, 1, noise, mu, ls, gs, bs, Wq, k_ws, v_ws,
                                 S_part, U_part);
  k_update<<<dim3(32), blk, 0, stream>>>(S_part, U_part, slots_a, 1, noise, mu, ls,
                                         W_ih, W_hh, b_ih, b_hh, gm, bm, W1, b1, W2,
                                         b2, slots_a, out, 0);
  // iter 1
  k_attn<<<g2, blk, 0, stream>>>(slots_a, 0, noise, mu, ls, gs, bs, Wq, k_ws, v_ws,
                                 S_part, U_part);
  k_update<<<dim3(32), blk, 0, stream>>>(S_part, U_part, slots_a, 0, noise, mu, ls,
                                         W_ih, W_hh, b_ih, b_hh, gm, bm, W1, b1, W2,
                                         b2, slots_b, out, 0);
  // iter 2 (writes slots to d_out)
  k_attn<<<g2, blk, 0, stream>>>(slots_b, 0, noise, mu, ls, gs, bs, Wq, k_ws, v_ws,
                                 S_part, U_part);
  k_update<<<dim3(32), blk, 0, stream>>>(S_part, U_part, slots_b, 0, noise, mu, ls,
                                         W_ih, W_hh, b_ih, b_hh, gm, bm, W1, b1, W2,
                                         b2, slots_a, out, 1);
  // final attention map
  k_final<<<g2, blk, 0, stream>>>(slots_a, gs, bs, Wq, k_ws, out + 16384);
}

// Round 2
// 212.853 us; speedup vs baseline: 1.0938x; 1.0938x over previous
//
#include <hip/hip_runtime.h>

typedef unsigned short u16;
typedef unsigned int   u32;
typedef __attribute__((ext_vector_type(8)))  short short8;
typedef __attribute__((ext_vector_type(4)))  float f32x4v;

#define DEVI __device__ __forceinline__

constexpr int   Bb = 32, Nn = 4096, Dd = 256, Kk = 8, SDd = 64, HDd = 128;
constexpr float EPSc = 1e-8f, LNEPS = 1e-5f, SCALEc = 0.125f;  // SD^-0.5

DEVI u16 f2b(float f) {            // f32 -> bf16 RNE
  u32 u = __builtin_bit_cast(u32, f);
  return (u16)((u + 0x7fffu + ((u >> 16) & 1u)) >> 16);
}
DEVI float b2f(u16 s) { return __builtin_bit_cast(float, ((u32)s) << 16); }
DEVI float sigmoidf_(float x) { return 1.f / (1.f + __expf(-x)); }

DEVI void gll16(const void* g, void* l) {   // async 16B/lane global->LDS
  __builtin_amdgcn_global_load_lds(
      (const __attribute__((address_space(1))) u32*)g,
      (__attribute__((address_space(3))) u32*)l, 16, 0, 0);
}

DEVI float dot64(const float* __restrict__ a, const float* __restrict__ w) {
  float s = 0.f;
  #pragma unroll
  for (int i = 0; i < 16; ++i) {
    float4 av = *(const float4*)(a + i * 4);
    float4 wv = *(const float4*)(w + i * 4);
    s += av.x * wv.x + av.y * wv.y + av.z * wv.z + av.w * wv.w;
  }
  return s;
}
DEVI float dot128(const float* __restrict__ a, const float* __restrict__ w) {
  float s = 0.f;
  #pragma unroll
  for (int i = 0; i < 32; ++i) {
    float4 av = *(const float4*)(a + i * 4);
    float4 wv = *(const float4*)(w + i * 4);
    s += av.x * wv.x + av.y * wv.y + av.z * wv.z + av.w * wv.w;
  }
  return s;
}

// LayerNorm of 8 rows x 64 cols living in LDS (256 threads).
DEVI void ln8(const float* src, float* dst, const float* __restrict__ g,
              const float* __restrict__ b, int t) {
  int l = t & 63, w = t >> 6;
  int r = w * 2 + (l >> 5), c = l & 31;
  float x0 = src[r * 64 + c], x1 = src[r * 64 + c + 32];
  float s = x0 + x1, q2 = x0 * x0 + x1 * x1;
  #pragma unroll
  for (int m = 1; m < 32; m <<= 1) { s += __shfl_xor(s, m); q2 += __shfl_xor(q2, m); }
  float mean = s * (1.f / 64.f);
  float rs = rsqrtf(q2 * (1.f / 64.f) - mean * mean + LNEPS);
  dst[r * 64 + c]      = (x0 - mean) * rs * g[c]      + b[c];
  dst[r * 64 + c + 32] = (x1 - mean) * rs * g[c + 32] + b[c + 32];
}

// ---------------------------------------------------------------------------
// K0: weights -> bf16 swizzle images (so consumers can global_load_lds
// linearly and ds_read swizzled; rule 21 both-sides-or-neither).
// wp image u16 idx = (n*256+k) ^ ((n&7)<<3); wk/wv: (n*64+k) ^ ((n&7)<<3).
// ---------------------------------------------------------------------------
__global__ __launch_bounds__(256) void k_prep(
    const float* __restrict__ Wp, const float* __restrict__ Wk,
    const float* __restrict__ Wv, u16* __restrict__ wp_sw,
    u16* __restrict__ wk_sw, u16* __restrict__ wv_sw) {
  int i = blockIdx.x * 256 + threadIdx.x;
  if (i < 16384) wp_sw[i ^ (((i >> 8) & 7) << 3)] = f2b(Wp[i]);
  if (i < 4096) {
    wk_sw[i ^ (((i >> 6) & 7) << 3)] = f2b(Wk[i]);
    wv_sw[i ^ (((i >> 6) & 7) << 3)] = f2b(Wv[i]);
  }
}

// ---------------------------------------------------------------------------
// K1: fused LN(256) -> proj(256->64)+bias -> LN(64) -> k,v (64->64), bf16 out.
// 64 rows/block, 4 waves x 16 rows, mfma_f32_16x16x32_bf16.
// Weights staged via async global_load_lds from pre-swizzled images.
// k_ws written as per-256-row-tile swizzle image; v_ws linear.
// ---------------------------------------------------------------------------
__global__ __launch_bounds__(256) void k_proj_kv(
    const float* __restrict__ in, const float* __restrict__ gpro,
    const float* __restrict__ bpro, const u16* __restrict__ wp_sw,
    const float* __restrict__ bproj, const float* __restrict__ gin,
    const float* __restrict__ bin, const u16* __restrict__ wk_sw,
    const u16* __restrict__ wv_sw, u16* __restrict__ k_ws,
    u16* __restrict__ v_ws) {
  __shared__ __align__(16) u16 wp_lds[64 * 256];
  __shared__ __align__(16) u16 wk_lds[64 * 64];
  __shared__ __align__(16) u16 wv_lds[64 * 64];
  __shared__ __align__(16) u16 xn_lds[64 * 64];
  __shared__ float gp_l[256], bp_l[256], bj_l[64], gn_l[64], bn_l[64];

  const int t = threadIdx.x;
  const int l = t & 63, w = t >> 6;

  // async staging: 8+2+2 x 16B per lane, zero VALU conversion
  {
    const char* wpg = (const char*)wp_sw;
    const char* wkg = (const char*)wk_sw;
    const char* wvg = (const char*)wv_sw;
    #pragma unroll
    for (int i = 0; i < 8; ++i) {
      int off = w * 8192 + i * 1024 + l * 16;
      gll16(wpg + off, (char*)wp_lds + off);
    }
    #pragma unroll
    for (int i = 0; i < 2; ++i) {
      int off = w * 2048 + i * 1024 + l * 16;
      gll16(wkg + off, (char*)wk_lds + off);
      gll16(wvg + off, (char*)wv_lds + off);
    }
  }
  gp_l[t] = gpro[t];
  bp_l[t] = bpro[t];
  if (t < 64) { bj_l[t] = bproj[t]; gn_l[t] = gin[t]; bn_l[t] = bin[t]; }

  const int r16 = l & 15, q4 = l >> 4;
  const long rowbase = (long)blockIdx.x * 64 + w * 16;
  const long grow = rowbase + r16;
  const float* rp = in + grow * 256;

  // load this lane's slices of its row; stats in f32, values packed to bf16
  short8 a[8];
  float sum = 0.f, sq = 0.f;
  #pragma unroll
  for (int ks = 0; ks < 8; ++ks) {
    float4 L0 = *(const float4*)(rp + ks * 32 + q4 * 8);
    float4 L1 = *(const float4*)(rp + ks * 32 + q4 * 8 + 4);
    sum += L0.x + L0.y + L0.z + L0.w + L1.x + L1.y + L1.z + L1.w;
    sq += L0.x * L0.x + L0.y * L0.y + L0.z * L0.z + L0.w * L0.w +
          L1.x * L1.x + L1.y * L1.y + L1.z * L1.z + L1.w * L1.w;
    a[ks][0] = (short)f2b(L0.x); a[ks][1] = (short)f2b(L0.y);
    a[ks][2] = (short)f2b(L0.z); a[ks][3] = (short)f2b(L0.w);
    a[ks][4] = (short)f2b(L1.x); a[ks][5] = (short)f2b(L1.y);
    a[ks][6] = (short)f2b(L1.z); a[ks][7] = (short)f2b(L1.w);
  }
  __syncthreads();  // staging (vmcnt) + smalls complete

  // row r16 lives in lanes {r16, r16+16, r16+32, r16+48}
  sum += __shfl_xor(sum, 16); sum += __shfl_xor(sum, 32);
  sq  += __shfl_xor(sq, 16);  sq  += __shfl_xor(sq, 32);
  float mean = sum * (1.f / 256.f);
  float rs = rsqrtf(sq * (1.f / 256.f) - mean * mean + LNEPS);
  #pragma unroll
  for (int ks = 0; ks < 8; ++ks) {
    #pragma unroll
    for (int j = 0; j < 8; ++j) {
      int kidx = ks * 32 + q4 * 8 + j;
      float x = b2f((u16)a[ks][j]);
      a[ks][j] = (short)f2b((x - mean) * rs * gp_l[kidx] + bp_l[kidx]);
    }
  }

  // proj GEMM: 16 rows x 64 cols, K=256
  f32x4v acc[4];
  #pragma unroll
  for (int nt = 0; nt < 4; ++nt)
    #pragma unroll
    for (int i = 0; i < 4; ++i) acc[nt][i] = 0.f;
  #pragma unroll
  for (int ks = 0; ks < 8; ++ks) {
    #pragma unroll
    for (int nt = 0; nt < 4; ++nt) {
      int n = nt * 16 + r16;
      int byte = (n * 512 + 64 * ks + 16 * q4) ^ ((n & 7) << 4);
      short8 bf = *(const short8*)((const char*)wp_lds + byte);
      acc[nt] = __builtin_amdgcn_mfma_f32_16x16x32_bf16(a[ks], bf, acc[nt], 0, 0, 0);
    }
  }
  // + b_proj
  #pragma unroll
  for (int nt = 0; nt < 4; ++nt) {
    float bb = bj_l[nt * 16 + r16];
    #pragma unroll
    for (int reg = 0; reg < 4; ++reg) acc[nt][reg] += bb;
  }
  // LN(64) per output row; write xn (bf16, swizzled) to LDS
  #pragma unroll
  for (int reg = 0; reg < 4; ++reg) {
    float s = acc[0][reg] + acc[1][reg] + acc[2][reg] + acc[3][reg];
    float q2 = acc[0][reg] * acc[0][reg] + acc[1][reg] * acc[1][reg] +
               acc[2][reg] * acc[2][reg] + acc[3][reg] * acc[3][reg];
    #pragma unroll
    for (int m = 1; m < 16; m <<= 1) { s += __shfl_xor(s, m); q2 += __shfl_xor(q2, m); }
    float mn = s * (1.f / 64.f);
    float rr = rsqrtf(q2 * (1.f / 64.f) - mn * mn + LNEPS);
    int row = q4 * 4 + reg;       // 0..15 within wave tile
    int rowg = w * 16 + row;
    #pragma unroll
    for (int nt = 0; nt < 4; ++nt) {
      int col = nt * 16 + r16;
      float y = (acc[nt][reg] - mn) * rr * gn_l[col] + bn_l[col];
      int byte = (rowg * 128 + 2 * col) ^ ((row & 7) << 4);
      *(u16*)((char*)xn_lds + byte) = f2b(y);
    }
  }
  __syncthreads();

  // k,v GEMMs: K=64
  f32x4v kacc[4], vacc[4];
  #pragma unroll
  for (int nt = 0; nt < 4; ++nt)
    #pragma unroll
    for (int i = 0; i < 4; ++i) { kacc[nt][i] = 0.f; vacc[nt][i] = 0.f; }
  #pragma unroll
  for (int ks = 0; ks < 2; ++ks) {
    int rowg2 = w * 16 + r16;
    int abyte = (rowg2 * 128 + 64 * ks + 16 * q4) ^ ((r16 & 7) << 4);
    short8 af = *(const short8*)((const char*)xn_lds + abyte);
    #pragma unroll
    for (int nt = 0; nt < 4; ++nt) {
      int n = nt * 16 + r16;
      int bbyte = (n * 128 + 64 * ks + 16 * q4) ^ ((n & 7) << 4);
      short8 bk = *(const short8*)((const char*)wk_lds + bbyte);
      short8 bv = *(const short8*)((const char*)wv_lds + bbyte);
      kacc[nt] = __builtin_amdgcn_mfma_f32_16x16x32_bf16(af, bk, kacc[nt], 0, 0, 0);
      vacc[nt] = __builtin_amdgcn_mfma_f32_16x16x32_bf16(af, bv, vacc[nt], 0, 0, 0);
    }
  }
  #pragma unroll
  for (int nt = 0; nt < 4; ++nt) {
    #pragma unroll
    for (int reg = 0; reg < 4; ++reg) {
      int row = q4 * 4 + reg;
      long gr = rowbase + row;          // global row = b*4096 + n
      int col = nt * 16 + r16;
      // k: per-256-row-tile swizzle image
      long tile = gr >> 8;
      int  r    = (int)(gr & 255);
      long ko = tile * 16384 + ((r * 64 + col) ^ ((r & 7) << 3));
      k_ws[ko] = f2b(kacc[nt][reg]);
      v_ws[gr * 64 + col] = f2b(vacc[nt][reg]);
    }
  }
}

// ---------------------------------------------------------------------------
// K2: per (b, 256-n tile): recompute sn,q; logits (k from swizzled LDS);
// softmax over slots; S = sum_n attn, U = sum_n attn*v (v from global).
// ---------------------------------------------------------------------------
__global__ __launch_bounds__(256) void k_attn(
    const float* __restrict__ slots_in, int init_slots,
    const float* __restrict__ noise, const float* __restrict__ mu,
    const float* __restrict__ ls, const float* __restrict__ gs,
    const float* __restrict__ bs, const float* __restrict__ Wq,
    const u16* __restrict__ k_sw, const u16* __restrict__ v_ws,
    float* __restrict__ S_part, float* __restrict__ U_part) {
  const int bx = blockIdx.x, by = blockIdx.y, t = threadIdx.x;
  const int l = t & 63, w = t >> 6;
  __shared__ __align__(16) u16 k_l[16384];   // 32KB; reused as ured after PV
  __shared__ float sl[512], snl[512], ql[512];
  __shared__ __align__(16) float attn_l[2048];
  __shared__ float sred[32];

  // stage k tile (swizzle image -> linear LDS copy keeps image)
  {
    const char* gsrc = (const char*)(k_sw + ((long)(by * 16 + bx)) * 16384);
    #pragma unroll
    for (int i = 0; i < 8; ++i) {
      int off = w * 8192 + i * 1024 + l * 16;
      gll16(gsrc + off, (char*)k_l + off);
    }
  }
  for (int i = t; i < 512; i += 256) {
    float v;
    if (init_slots) { int d = i & 63; v = mu[d] + __expf(ls[d]) * noise[by * 512 + i]; }
    else v = slots_in[by * 512 + i];
    sl[i] = v;
  }
  __syncthreads();
  ln8(sl, snl, gs, bs, t);
  __syncthreads();
  {
    int kk = t >> 6, d = t & 63;
    ql[kk * 64 + d]       = SCALEc * dot64(snl + kk * 64, Wq + d * 64);
    ql[(kk + 4) * 64 + d] = SCALEc * dot64(snl + (kk + 4) * 64, Wq + d * 64);
  }
  __syncthreads();

  // logits for n = bx*256 + t; k row from swizzled LDS, conflict-minimal b128
  short8 kw8[8];
  #pragma unroll
  for (int j = 0; j < 8; ++j)
    kw8[j] = *(const short8*)((const char*)k_l + ((t * 128 + 16 * j) ^ ((t & 7) << 4)));
  float lg[8];
  #pragma unroll
  for (int i = 0; i < 8; ++i) lg[i] = 0.f;
  #pragma unroll
  for (int c4 = 0; c4 < 16; ++c4) {
    int j = c4 >> 1, e0 = (c4 & 1) * 4;
    float f0 = b2f((u16)kw8[j][e0]);
    float f1 = b2f((u16)kw8[j][e0 + 1]);
    float f2v = b2f((u16)kw8[j][e0 + 2]);
    float f3 = b2f((u16)kw8[j][e0 + 3]);
    #pragma unroll
    for (int kk = 0; kk < 8; ++kk) {
      float4 qv = *(const float4*)(ql + kk * 64 + c4 * 4);
      lg[kk] += qv.x * f0 + qv.y * f1 + qv.z * f2v + qv.w * f3;
    }
  }
  float mx = lg[0];
  #pragma unroll
  for (int kk = 1; kk < 8; ++kk) mx = fmaxf(mx, lg[kk]);
  float e[8], ss = 0.f;
  #pragma unroll
  for (int kk = 0; kk < 8; ++kk) { e[kk] = __expf(lg[kk] - mx); ss += e[kk]; }
  float inv = 1.f / ss;
  #pragma unroll
  for (int kk = 0; kk < 8; ++kk) e[kk] *= inv;
  float4 A0 = {e[0], e[1], e[2], e[3]}, A1 = {e[4], e[5], e[6], e[7]};
  *(float4*)(attn_l + t * 8) = A0;
  *(float4*)(attn_l + t * 8 + 4) = A1;
  __syncthreads();   // last k_l read above -> safe to reuse k_l after this

  // attn @ v : wave owns 64-n strip, lane owns d-pair p; v straight from L2/L3
  float au[8][2];
  #pragma unroll
  for (int i = 0; i < 8; ++i) { au[i][0] = 0.f; au[i][1] = 0.f; }
  const int p = l & 31, g = l >> 5;
  const u32* vw = (const u32*)(v_ws + ((long)by * Nn + bx * 256 + w * 64) * 64);
  #pragma unroll 8
  for (int nn = 0; nn < 32; ++nn) {
    int n = nn * 2 + g;
    float4 a0 = *(const float4*)(attn_l + (w * 64 + n) * 8);
    float4 a1 = *(const float4*)(attn_l + (w * 64 + n) * 8 + 4);
    u32 vv = vw[n * 32 + p];
    float vlo = b2f((u16)(vv & 0xffff)), vhi = b2f((u16)(vv >> 16));
    au[0][0] += a0.x * vlo; au[0][1] += a0.x * vhi;
    au[1][0] += a0.y * vlo; au[1][1] += a0.y * vhi;
    au[2][0] += a0.z * vlo; au[2][1] += a0.z * vhi;
    au[3][0] += a0.w * vlo; au[3][1] += a0.w * vhi;
    au[4][0] += a1.x * vlo; au[4][1] += a1.x * vhi;
    au[5][0] += a1.y * vlo; au[5][1] += a1.y * vhi;
    au[6][0] += a1.z * vlo; au[6][1] += a1.z * vhi;
    au[7][0] += a1.w * vlo; au[7][1] += a1.w * vhi;
  }
  #pragma unroll
  for (int kk = 0; kk < 8; ++kk) {
    au[kk][0] += __shfl_xor(au[kk][0], 32);
    au[kk][1] += __shfl_xor(au[kk][1], 32);
  }
  float* ured = (float*)k_l;               // reuse (all reads fenced above)
  if (l < 32) {
    #pragma unroll
    for (int kk = 0; kk < 8; ++kk) {
      ured[w * 512 + kk * 64 + 2 * p]     = au[kk][0];
      ured[w * 512 + kk * 64 + 2 * p + 1] = au[kk][1];
    }
  }
  float s8[8];
  #pragma unroll
  for (int kk = 0; kk < 8; ++kk) {
    s8[kk] = e[kk];
    #pragma unroll
    for (int m = 1; m < 64; m <<= 1) s8[kk] += __shfl_xor(s8[kk], m);
  }
  if (l == 0) {
    #pragma unroll
    for (int kk = 0; kk < 8; ++kk) sred[w * 8 + kk] = s8[kk];
  }
  __syncthreads();
  for (int i = t; i < 512; i += 256)
    U_part[((long)(by * 16 + bx)) * 512 + i] =
        ured[i] + ured[512 + i] + ured[1024 + i] + ured[1536 + i];
  if (t < 8)
    S_part[(by * 16 + bx) * 8 + t] = sred[t] + sred[8 + t] + sred[16 + t] + sred[24 + t];
}

// ---------------------------------------------------------------------------
// K3: reduce partials, updates = U/(S+eps), GRU, residual MLP -> new slots.
// ---------------------------------------------------------------------------
__global__ __launch_bounds__(256) void k_update(
    const float* __restrict__ S_part, const float* __restrict__ U_part,
    const float* __restrict__ slots_in, int init_slots,
    const float* __restrict__ noise, const float* __restrict__ mu,
    const float* __restrict__ ls, const float* __restrict__ W_ih,
    const float* __restrict__ W_hh, const float* __restrict__ b_ih,
    const float* __restrict__ b_hh, const float* __restrict__ gm,
    const float* __restrict__ bm, const float* __restrict__ W1,
    const float* __restrict__ b1, const float* __restrict__ W2,
    const float* __restrict__ b2, float* __restrict__ slots_out,
    float* __restrict__ out_slots, int write_out) {
  const int b = blockIdx.x, t = threadIdx.x;
  __shared__ float u_l[512], sp[512], gi[1536], gh[1536], sn2[512], mi[512],
      h1[1024], Ssum[8];
  if (t < 8) {
    float s = 0.f;
    #pragma unroll
    for (int ch = 0; ch < 16; ++ch) s += S_part[(b * 16 + ch) * 8 + t];
    Ssum[t] = s;
  }
  for (int i = t; i < 512; i += 256) {
    float v;
    if (init_slots) { int d = i & 63; v = mu[d] + __expf(ls[d]) * noise[b * 512 + i]; }
    else v = slots_in[b * 512 + i];
    sp[i] = v;
  }
  __syncthreads();
  for (int i = t; i < 512; i += 256) {
    float s = 0.f;
    #pragma unroll
    for (int ch = 0; ch < 16; ++ch) s += U_part[((long)(b * 16 + ch)) * 512 + i];
    u_l[i] = s / (Ssum[i >> 6] + EPSc);
  }
  __syncthreads();
  for (int i = t; i < 1536; i += 256) {
    int kk = i / 192, j = i - kk * 192;
    gi[i] = b_ih[j] + dot64(u_l + kk * 64, W_ih + j * 64);
    gh[i] = b_hh[j] + dot64(sp + kk * 64, W_hh + j * 64);
  }
  __syncthreads();
  for (int i = t; i < 512; i += 256) {
    int kk = i >> 6, d = i & 63, base = kk * 192;
    float r = sigmoidf_(gi[base + d] + gh[base + d]);
    float z = sigmoidf_(gi[base + 64 + d] + gh[base + 64 + d]);
    float nn = tanhf(gi[base + 128 + d] + r * gh[base + 128 + d]);
    sn2[i] = (1.f - z) * nn + z * sp[i];
  }
  __syncthreads();
  ln8(sn2, mi, gm, bm, t);
  __syncthreads();
  for (int i = t; i < 1024; i += 256) {
    int kk = i >> 7, j = i & 127;
    h1[i] = fmaxf(b1[j] + dot64(mi + kk * 64, W1 + j * 64), 0.f);
  }
  __syncthreads();
  for (int i = t; i < 512; i += 256) {
    int kk = i >> 6, d = i & 63;
    float s = sn2[i] + b2[d] + dot128(h1 + kk * 128, W2 + d * 128);
    slots_out[b * 512 + i] = s;
    if (write_out) out_slots[b * 512 + i] = s;
  }
}

// ---------------------------------------------------------------------------
// K4: final attention -> d_out (f32), softmax over slots, not n-normalized.
// ---------------------------------------------------------------------------
__global__ __launch_bounds__(256) void k_final(
    const float* __restrict__ slots_in, const float* __restrict__ gs,
    const float* __restrict__ bs, const float* __restrict__ Wq,
    const u16* __restrict__ k_sw, float* __restrict__ outA) {
  const int bx = blockIdx.x, by = blockIdx.y, t = threadIdx.x;
  const int l = t & 63, w = t >> 6;
  __shared__ __align__(16) u16 k_l[16384];
  __shared__ float sl[512], snl[512], ql[512];
  {
    const char* gsrc = (const char*)(k_sw + ((long)(by * 16 + bx)) * 16384);
    #pragma unroll
    for (int i = 0; i < 8; ++i) {
      int off = w * 8192 + i * 1024 + l * 16;
      gll16(gsrc + off, (char*)k_l + off);
    }
  }
  for (int i = t; i < 512; i += 256) sl[i] = slots_in[by * 512 + i];
  __syncthreads();
  ln8(sl, snl, gs, bs, t);
  __syncthreads();
  {
    int kk = t >> 6, d = t & 63;
    ql[kk * 64 + d]       = SCALEc * dot64(snl + kk * 64, Wq + d * 64);
    ql[(kk + 4) * 64 + d] = SCALEc * dot64(snl + (kk + 4) * 64, Wq + d * 64);
  }
  __syncthreads();
  short8 kw8[8];
  #pragma unroll
  for (int j = 0; j < 8; ++j)
    kw8[j] = *(const short8*)((const char*)k_l + ((t * 128 + 16 * j) ^ ((t & 7) << 4)));
  float lg[8];
  #pragma unroll
  for (int i = 0; i < 8; ++i) lg[i] = 0.f;
  #pragma unroll
  for (int c4 = 0; c4 < 16; ++c4) {
    int j = c4 >> 1, e0 = (c4 & 1) * 4;
    float f0 = b2f((u16)kw8[j][e0]);
    float f1 = b2f((u16)kw8[j][e0 + 1]);
    float f2v = b2f((u16)kw8[j][e0 + 2]);
    float f3 = b2f((u16)kw8[j][e0 + 3]);
    #pragma unroll
    for (int kk = 0; kk < 8; ++kk) {
      float4 qv = *(const float4*)(ql + kk * 64 + c4 * 4);
      lg[kk] += qv.x * f0 + qv.y * f1 + qv.z * f2v + qv.w * f3;
    }
  }
  float mx = lg[0];
  #pragma unroll
  for (int kk = 1; kk < 8; ++kk) mx = fmaxf(mx, lg[kk]);
  float e[8], ss = 0.f;
  #pragma unroll
  for (int kk = 0; kk < 8; ++kk) { e[kk] = __expf(lg[kk] - mx); ss += e[kk]; }
  float inv = 1.f / ss;
  int n = bx * 256 + t;
  #pragma unroll
  for (int kk = 0; kk < 8; ++kk)
    outA[((long)by * 8 + kk) * 4096 + n] = e[kk] * inv;
}

extern "C" void kernel_launch(void* const* d_in, const int* in_sizes, int n_in,
                              void* d_out, int out_size, void* d_ws, size_t ws_size,
                              hipStream_t stream) {
  (void)in_sizes; (void)n_in; (void)out_size; (void)ws_size;
  const float* in    = (const float*)d_in[0];
  const float* noise = (const float*)d_in[1];
  const float* mu    = (const float*)d_in[2];
  const float* ls    = (const float*)d_in[3];
  const float* gpro  = (const float*)d_in[4];
  const float* bpro  = (const float*)d_in[5];
  const float* Wp    = (const float*)d_in[6];
  const float* bproj = (const float*)d_in[7];
  const float* Wq    = (const float*)d_in[8];
  const float* Wk    = (const float*)d_in[9];
  const float* Wv    = (const float*)d_in[10];
  const float* W_ih  = (const float*)d_in[11];
  const float* W_hh  = (const float*)d_in[12];
  const float* b_ih  = (const float*)d_in[13];
  const float* b_hh  = (const float*)d_in[14];
  const float* W1    = (const float*)d_in[15];
  const float* b1    = (const float*)d_in[16];
  const float* W2    = (const float*)d_in[17];
  const float* b2    = (const float*)d_in[18];
  const float* gin   = (const float*)d_in[19];
  const float* bin   = (const float*)d_in[20];
  const float* gs    = (const float*)d_in[21];
  const float* bs    = (const float*)d_in[22];
  const float* gm    = (const float*)d_in[23];
  const float* bm    = (const float*)d_in[24];

  char* ws = (char*)d_ws;
  u16* k_ws      = (u16*)ws;                                   // 16 MiB (tile-swizzled)
  u16* v_ws      = (u16*)(ws + 16777216);                      // 16 MiB
  float* slots_a = (float*)(ws + 33554432);                    // 64 KiB
  float* slots_b = (float*)(ws + 33554432 + 65536);            // 64 KiB
  float* S_part  = (float*)(ws + 33554432 + 131072);           // 16 KiB
  float* U_part  = (float*)(ws + 33554432 + 131072 + 16384);   // 1 MiB
  u16* wp_sw     = (u16*)(ws + 33554432 + 131072 + 16384 + 1048576);  // 32 KiB
  u16* wk_sw     = wp_sw + 16384;                              // 8 KiB
  u16* wv_sw     = wk_sw + 4096;                               // 8 KiB
  float* out = (float*)d_out;

  k_prep<<<dim3(64), dim3(256), 0, stream>>>(Wp, Wk, Wv, wp_sw, wk_sw, wv_sw);
  k_proj_kv<<<dim3(2048), dim3(256), 0, stream>>>(in, gpro, bpro, wp_sw, bproj,
                                                  gin, bin, wk_sw, wv_sw, k_ws, v_ws);
  dim3 g2(16, 32), blk(256);
  // iter 0 (slots initialized in-kernel from mu/ls/noise)
  k_attn<<<g2, blk, 0, stream>>>(slots_a, 1, noise, mu, ls, gs, bs, Wq, k_ws, v_ws,
                                 S_part, U_part);
  k_update<<<dim3(32), blk, 0, stream>>>(S_part, U_part, slots_a, 1, noise, mu, ls,
                                         W_ih, W_hh, b_ih, b_hh, gm, bm, W1, b1, W2,
                                         b2, slots_a, out, 0);
  // iter 1
  k_attn<<<g2, blk, 0, stream>>>(slots_a, 0, noise, mu, ls, gs, bs, Wq, k_ws, v_ws,
                                 S_part, U_part);
  k_update<<<dim3(32), blk, 0, stream>>>(S_part, U_part, slots_a, 0, noise, mu, ls,
                                         W_ih, W_hh, b_ih, b_hh, gm, bm, W1, b1, W2,
                                         b2, slots_b, out, 0);
  // iter 2 (writes slots to d_out)
  k_attn<<<g2, blk, 0, stream>>>(slots_b, 0, noise, mu, ls, gs, bs, Wq, k_ws, v_ws,
                                 S_part, U_part);
  k_update<<<dim3(32), blk, 0, stream>>>(S_part, U_part, slots_b, 0, noise, mu, ls,
                                         W_ih, W_hh, b_ih, b_hh, gm, bm, W1, b1, W2,
                                         b2, slots_a, out, 1);
  // final attention map
  k_final<<<g2, blk, 0, stream>>>(slots_a, gs, bs, Wq, k_ws, out + 16384);
}